// Round 7
// baseline (1932.891 us; speedup 1.0000x reference)
//
#include <hip/hip_runtime.h>
#include <hip/hip_fp16.h>

#define B_ 256
#define T_ 1200
#define I_ 16
#define H_ 128

typedef __attribute__((ext_vector_type(2))) _Float16 h2;
typedef __attribute__((ext_vector_type(8))) _Float16 f16x8;

union f16x8u { f16x8 v; h2 h[4]; _Float16 s[8]; };

#if __has_builtin(__builtin_amdgcn_fdot2)
__device__ __forceinline__ float fdot2(h2 a, h2 b, float c) {
  return __builtin_amdgcn_fdot2(a, b, c, false);  // v_dot2_f32_f16
}
#else
__device__ __forceinline__ float fdot2(h2 a, h2 b, float c) {
  return fmaf((float)a.x, (float)b.x, fmaf((float)a.y, (float)b.y, c));
}
#endif

// broadcast one quad lane to all 4 (DPP quad_perm). PAT compile-time const.
template <int PAT>
__device__ __forceinline__ float qbcast(float x) {
  return __int_as_float(__builtin_amdgcn_update_dpp(0, __float_as_int(x), PAT, 0xF, 0xF, true));
}

// reduce quad-uniform values across the 16 quads of a wave
__device__ __forceinline__ float wred(float x) {
  x += __int_as_float(__builtin_amdgcn_update_dpp(0, __float_as_int(x), 0x141, 0xF, 0xF, true)); // row_half_mirror ~ xor4
  x += __int_as_float(__builtin_amdgcn_update_dpp(0, __float_as_int(x), 0x140, 0xF, 0xF, true)); // row_mirror ~ xor8
  x += __shfl_xor(x, 16);
  x += __shfl_xor(x, 32);
  return x;
}

__device__ __forceinline__ float tanh_(float x) {
  return 1.f - 2.f * __builtin_amdgcn_rcpf(1.f + __expf(2.f * x));
}

// Load a 128-wide f32 weight row as 64 fp16x2 into regs.
__device__ __forceinline__ void load_row_h2(const float* __restrict__ p, h2* w) {
#pragma unroll
  for (int i = 0; i < 32; ++i) {
    const float4 v = *(const float4*)(p + 4 * i);
    w[2 * i].x     = (_Float16)v.x; w[2 * i].y     = (_Float16)v.y;
    w[2 * i + 1].x = (_Float16)v.z; w[2 * i + 1].y = (_Float16)v.w;
  }
}

// raw workgroup barrier: drain LDS ops only (NOT vmcnt) -> global stores and
// loads stay in flight across the barrier. __syncthreads would force
// s_waitcnt vmcnt(0) every step (the measured ~70% stall).
__device__ __forceinline__ void lds_barrier() {
  __builtin_amdgcn_sched_barrier(0);
  asm volatile("s_waitcnt lgkmcnt(0)" ::: "memory");
  __builtin_amdgcn_s_barrier();
  __builtin_amdgcn_sched_barrier(0);
}

// ---------------------------------------------------------------------------
// Fully fused 2-layer LSTM + head, ONE kernel, 1 block (512 thr) per batch row.
// Thread owns gate-row g = q*128+j of BOTH layers (Whh0, Wih0, Wih1, Whh1 rows
// in the 256-reg unified file; AGPR-resident weights read tax-free by VALU).
// Layer 1 runs ONE STEP BEHIND layer 0 in the same region:
//   region u: L0 computes h0_u (dot over h0b[rb]=h0_{u-1}, x_u from LDS);
//             L1 computes h1_{u-1} (ih-dot reuses the SAME h0b[rb] reads,
//             hh-dot over h1b[rb]=h1_{u-2}).
// One lgkm-only barrier per region; head reduction (wred + ds_bpermute) for
// h1_{u-2} is deferred to region u (off the pre-barrier critical path,
// overlaps region-u dots). Rotating collector emits out[u-3] per region as a
// fire-and-forget global store. 1203 serial regions total (vs 2400 split).
// h0 never touches global memory. ZERO workspace.
// ---------------------------------------------------------------------------
__global__ __launch_bounds__(512, 2) void lstm_one(
    const float* __restrict__ xin,
    const float* __restrict__ Wih0, const float* __restrict__ Whh0,
    const float* __restrict__ bih0, const float* __restrict__ bhh0,
    const float* __restrict__ Wih1, const float* __restrict__ Whh1,
    const float* __restrict__ bih1, const float* __restrict__ bhh1,
    const float* __restrict__ Wlin, const float* __restrict__ blin,
    float* __restrict__ out)
{
  __shared__ __align__(16) __half xs[T_ * I_];    // 38400 B, staged once
  __shared__ __align__(16) __half h0b[2][H_];
  __shared__ __align__(16) __half h1b[2][H_];
  __shared__ __align__(16) float red[2][8];

  const int tid = threadIdx.x;
  const int q = tid & 3;
  const int j = tid >> 2;
  const int g = q * H_ + j;
  const int b = blockIdx.x;

  // stage x[b] -> LDS fp16 (coalesced float4 reads)
  {
    const float4* xg4 = (const float4*)(xin + (size_t)b * T_ * I_);
    for (int idx = tid; idx < T_ * I_ / 4; idx += 512) {
      const float4 v = xg4[idx];
      xs[4 * idx]     = __float2half(v.x);
      xs[4 * idx + 1] = __float2half(v.y);
      xs[4 * idx + 2] = __float2half(v.z);
      xs[4 * idx + 3] = __float2half(v.w);
    }
  }

  h2 w0[64], wi[64], w1[64], wx[8];   // 200 h2 = 200 unified regs of weights
  load_row_h2(Whh0 + (size_t)g * H_, w0);
  load_row_h2(Wih1 + (size_t)g * H_, wi);
  load_row_h2(Whh1 + (size_t)g * H_, w1);
  {
    const float* px = Wih0 + (size_t)g * I_;
#pragma unroll
    for (int i = 0; i < 4; ++i) {
      const float4 v = *(const float4*)(px + 4 * i);
      wx[2 * i].x     = (_Float16)v.x; wx[2 * i].y     = (_Float16)v.y;
      wx[2 * i + 1].x = (_Float16)v.z; wx[2 * i + 1].y = (_Float16)v.w;
    }
  }
  const float bs0 = bih0[g] + bhh0[g];
  const float bs1 = bih1[g] + bhh1[g];
  const float wl = Wlin[j];   // quad-uniform; wred sums quads only
  const float bl = blin[0];
  // branch-free activation: gate q==2 -> tanh, else sigmoid
  const float s0 = (q == 2) ? 1.f : 0.f;
  const float s1 = (q == 2) ? -2.f : 1.f;
  const float s2 = (q == 2) ? 2.f : -1.f;

  if (tid < H_) {
    h0b[0][tid] = __float2half(0.f);
    h1b[0][tid] = __float2half(0.f);
    h1b[1][tid] = __float2half(0.f);
  }
  float cst0 = 0.f, cst1 = 0.f, hv1p = 0.f;
  float* op = out + (size_t)b * T_;
  __syncthreads();   // one full sync after staging (drains x loads too)

#pragma unroll 1
  for (int u = 0; u <= T_ + 2; ++u) {
    const int rb = u & 1, nb = rb ^ 1;

    // ---- deferred head for h1_{u-2} (in regs from last region) ----
    if (u >= 2 && u <= T_ + 1) {
      const float val = wred(fmaxf(hv1p, 0.f) * wl);
      if ((tid & 63) == 0) red[rb][tid >> 6] = val;    // slot (u-2)&1 == rb
    }
    // ---- rotating collector: emit out[u-3] (red written last region) ----
    if (u >= 3) {
      const int m = u - 3;
      if (tid == ((m & 7) << 6)) {
        const float4 r0 = *(const float4*)(&red[nb][0]);  // slot (u-3)&1 == nb
        const float4 r1 = *(const float4*)(&red[nb][4]);
        op[m] = bl + r0.x + r0.y + r0.z + r0.w + r1.x + r1.y + r1.z + r1.w;
      }
    }

    float A0 = 0.f, A1 = 0.f, A2 = 0.f, A3 = 0.f;   // L0 hh-acc
    float B0 = 0.f, B1 = 0.f, B2 = 0.f, B3 = 0.f;   // L1 ih-acc
    float C0 = 0.f, C1 = 0.f, C2 = 0.f, C3 = 0.f;   // L1 hh-acc

    if (u >= 1 && u < T_) {
      // fused: read h0b[rb] (= h0_{u-1}) ONCE, feed both Whh0 and Wih1 dots
#pragma unroll
      for (int i = 0; i < 16; ++i) {
        f16x8u u8; u8.v = *(const f16x8*)(&h0b[rb][8 * i]);
        A0 = fdot2(w0[4 * i],     u8.h[0], A0);
        A1 = fdot2(w0[4 * i + 1], u8.h[1], A1);
        A2 = fdot2(w0[4 * i + 2], u8.h[2], A2);
        A3 = fdot2(w0[4 * i + 3], u8.h[3], A3);
        B0 = fdot2(wi[4 * i],     u8.h[0], B0);
        B1 = fdot2(wi[4 * i + 1], u8.h[1], B1);
        B2 = fdot2(wi[4 * i + 2], u8.h[2], B2);
        B3 = fdot2(wi[4 * i + 3], u8.h[3], B3);
      }
    } else if (u == T_) {
      // last L1 step still needs ih-dot over h0_{T-1}
#pragma unroll
      for (int i = 0; i < 16; ++i) {
        f16x8u u8; u8.v = *(const f16x8*)(&h0b[rb][8 * i]);
        B0 = fdot2(wi[4 * i],     u8.h[0], B0);
        B1 = fdot2(wi[4 * i + 1], u8.h[1], B1);
        B2 = fdot2(wi[4 * i + 2], u8.h[2], B2);
        B3 = fdot2(wi[4 * i + 3], u8.h[3], B3);
      }
    }
    // (u == 0: h0_{-1} = 0, hh-dot contributes nothing -> skipped)

    if (u < T_) {   // ---- layer-0 cell for step u ----
#pragma unroll
      for (int m2 = 0; m2 < 2; ++m2) {
        f16x8u u8; u8.v = *(const f16x8*)(&xs[u * I_ + 8 * m2]);
        A0 = fdot2(wx[4 * m2],     u8.h[0], A0);
        A1 = fdot2(wx[4 * m2 + 1], u8.h[1], A1);
        A2 = fdot2(wx[4 * m2 + 2], u8.h[2], A2);
        A3 = fdot2(wx[4 * m2 + 3], u8.h[3], A3);
      }
      const float pre = (A0 + A1) + (A2 + A3) + bs0;
      const float act = fmaf(s1, __builtin_amdgcn_rcpf(1.f + __expf(s2 * pre)), s0);
      const float ig = qbcast<0x00>(act);
      const float fg = qbcast<0x55>(act);
      const float gg = qbcast<0xAA>(act);
      const float og = qbcast<0xFF>(act);
      cst0 = fg * cst0 + ig * gg;
      const float hv0 = og * tanh_(cst0);
      if (q == 0) h0b[nb][j] = __float2half(hv0);
    }

    if (u >= 1 && u <= T_) {   // ---- layer-1 cell for step u-1 ----
#pragma unroll
      for (int i = 0; i < 16; ++i) {
        f16x8u u8; u8.v = *(const f16x8*)(&h1b[rb][8 * i]);   // h1_{u-2}
        C0 = fdot2(w1[4 * i],     u8.h[0], C0);
        C1 = fdot2(w1[4 * i + 1], u8.h[1], C1);
        C2 = fdot2(w1[4 * i + 2], u8.h[2], C2);
        C3 = fdot2(w1[4 * i + 3], u8.h[3], C3);
      }
      const float pre = (B0 + B1) + (B2 + B3) + (C0 + C1) + (C2 + C3) + bs1;
      const float act = fmaf(s1, __builtin_amdgcn_rcpf(1.f + __expf(s2 * pre)), s0);
      const float ig = qbcast<0x00>(act);
      const float fg = qbcast<0x55>(act);
      const float gg = qbcast<0xAA>(act);
      const float og = qbcast<0xFF>(act);
      cst1 = fg * cst1 + ig * gg;
      hv1p = og * tanh_(cst1);
      if (q == 0) h1b[nb][j] = __float2half(hv1p);
    }

    if (u <= T_ + 1) lds_barrier();
  }
}

extern "C" void kernel_launch(void* const* d_in, const int* in_sizes, int n_in,
                              void* d_out, int out_size, void* d_ws, size_t ws_size,
                              hipStream_t stream) {
  // Single fused kernel; zero workspace (d_ws unused).
  lstm_one<<<B_, 512, 0, stream>>>(
      (const float*)d_in[0],
      (const float*)d_in[1], (const float*)d_in[2],
      (const float*)d_in[3], (const float*)d_in[4],
      (const float*)d_in[5], (const float*)d_in[6],
      (const float*)d_in[7], (const float*)d_in[8],
      (const float*)d_in[9], (const float*)d_in[10],
      (float*)d_out);
}